// Round 1
// baseline (429.582 us; speedup 1.0000x reference)
//
#include <hip/hip_runtime.h>

// Mamba block, MI355X. Pipeline:
//  ln -> bf16 h -> [MFMA gemm] xz -> conv+silu -> [gemm] x_dbl -> [gemm+softplus] dt
//  -> selective scan (fp32, LDS-chunked, DPP 16-lane reduce) -> y_bf16 -> [gemm+resid] out
// ws budget ~103 MB (see kernel_launch offsets).

typedef unsigned short u16;
typedef unsigned int u32;

typedef __bf16 bf16x8 __attribute__((ext_vector_type(8)));
typedef float f32x4 __attribute__((ext_vector_type(4)));

__device__ __forceinline__ u16 f2bf(float f) {
  u32 u = __float_as_uint(f);
  u32 r = u + 0x7FFFu + ((u >> 16) & 1u);  // RNE
  return (u16)(r >> 16);
}

// ---------------- LayerNorm -> bf16 ----------------
__global__ __launch_bounds__(256) void ln_bf16_kernel(
    const float* __restrict__ x, const float* __restrict__ w,
    const float* __restrict__ b, u16* __restrict__ h) {
  const int row = blockIdx.x;
  const int tid = threadIdx.x;
  const float4 v = ((const float4*)(x + (size_t)row * 1024))[tid];
  float s = v.x + v.y + v.z + v.w;
  float s2 = v.x * v.x + v.y * v.y + v.z * v.z + v.w * v.w;
  for (int off = 32; off >= 1; off >>= 1) {
    s += __shfl_xor(s, off);
    s2 += __shfl_xor(s2, off);
  }
  __shared__ float red[8];
  const int wave = tid >> 6;
  if ((tid & 63) == 0) { red[wave * 2] = s; red[wave * 2 + 1] = s2; }
  __syncthreads();
  s = red[0] + red[2] + red[4] + red[6];
  s2 = red[1] + red[3] + red[5] + red[7];
  const float mu = s * (1.0f / 1024.0f);
  const float var = s2 * (1.0f / 1024.0f) - mu * mu;
  const float rstd = rsqrtf(var + 1e-5f);
  const float4 wv = ((const float4*)w)[tid];
  const float4 bv = ((const float4*)b)[tid];
  ushort4 o;
  o.x = f2bf((v.x - mu) * rstd * wv.x + bv.x);
  o.y = f2bf((v.y - mu) * rstd * wv.y + bv.y);
  o.z = f2bf((v.z - mu) * rstd * wv.z + bv.z);
  o.w = f2bf((v.w - mu) * rstd * wv.w + bv.w);
  ((ushort4*)(h + (size_t)row * 1024))[tid] = o;
}

// ---------------- fp32 -> bf16 converts ----------------
__global__ __launch_bounds__(256) void f32_to_bf16_kernel(
    const float* __restrict__ src, u16* __restrict__ dst, int n) {
  int i = blockIdx.x * 256 + threadIdx.x;
  if (i < n) dst[i] = f2bf(src[i]);
}

// x_dbl[:, :64] -> bf16 [M,64]
__global__ __launch_bounds__(256) void dtr_bf16_kernel(
    const float* __restrict__ xdbl, u16* __restrict__ dst) {
  int i = blockIdx.x * 256 + threadIdx.x;  // 2048*64
  int m = i >> 6, r = i & 63;
  dst[i] = f2bf(xdbl[(size_t)m * 96 + r]);
}

// ---------------- generic bf16 MFMA GEMM, C = A @ W^T ----------------
// A [M,K] bf16 row-major, W [N,K] bf16 row-major, C [M,N] f32.
// EPI: 0 none, 1 C += extra[m*N+n] (residual), 2 C = softplus(C + extra[n])
template <int EPI>
__global__ __launch_bounds__(256) void gemm_bt(
    const u16* __restrict__ A, const u16* __restrict__ W,
    float* __restrict__ C, const float* __restrict__ extra,
    int M, int N, int K) {
  const int n0 = blockIdx.x * 64;
  const int m0 = blockIdx.y * 64;
  __shared__ u16 As[64 * 32];
  __shared__ u16 Ws[64 * 32];
  const int tid = threadIdx.x;
  const int wave = tid >> 6;
  const int lane = tid & 63;
  const int wm = (wave >> 1) * 32;
  const int wn = (wave & 1) * 32;
  const int lrow = tid >> 2;       // 0..63 staging row
  const int lcg = (tid & 3) * 8;   // staging k-chunk (8 bf16 = 16B)
  const int arow = m0 + lrow;
  const int wrow = n0 + lrow;
  f32x4 acc[2][2];
#pragma unroll
  for (int i = 0; i < 2; ++i)
#pragma unroll
    for (int j = 0; j < 2; ++j) acc[i][j] = (f32x4){0.f, 0.f, 0.f, 0.f};

  const int fm = lane & 15;
  const int fk = (lane >> 4) * 8;

  for (int k0 = 0; k0 < K; k0 += 32) {
    uint4 av = *(const uint4*)(A + (size_t)arow * K + k0 + lcg);
    uint4 wv = make_uint4(0u, 0u, 0u, 0u);
    if (wrow < N) wv = *(const uint4*)(W + (size_t)wrow * K + k0 + lcg);
    __syncthreads();
    *(uint4*)(As + lrow * 32 + lcg) = av;
    *(uint4*)(Ws + lrow * 32 + lcg) = wv;
    __syncthreads();
    bf16x8 a0 = *(const bf16x8*)(As + (wm + fm) * 32 + fk);
    bf16x8 a1 = *(const bf16x8*)(As + (wm + 16 + fm) * 32 + fk);
    bf16x8 b0 = *(const bf16x8*)(Ws + (wn + fm) * 32 + fk);
    bf16x8 b1 = *(const bf16x8*)(Ws + (wn + 16 + fm) * 32 + fk);
    acc[0][0] = __builtin_amdgcn_mfma_f32_16x16x32_bf16(a0, b0, acc[0][0], 0, 0, 0);
    acc[0][1] = __builtin_amdgcn_mfma_f32_16x16x32_bf16(a0, b1, acc[0][1], 0, 0, 0);
    acc[1][0] = __builtin_amdgcn_mfma_f32_16x16x32_bf16(a1, b0, acc[1][0], 0, 0, 0);
    acc[1][1] = __builtin_amdgcn_mfma_f32_16x16x32_bf16(a1, b1, acc[1][1], 0, 0, 0);
  }

  const int col = lane & 15;
  const int rbase = (lane >> 4) * 4;
#pragma unroll
  for (int tm = 0; tm < 2; ++tm)
#pragma unroll
    for (int tn = 0; tn < 2; ++tn)
#pragma unroll
      for (int r = 0; r < 4; ++r) {
        int m = m0 + wm + tm * 16 + rbase + r;
        int n = n0 + wn + tn * 16 + col;
        if (n < N) {
          float v = acc[tm][tn][r];
          if (EPI == 1) v += extra[(size_t)m * N + n];
          if (EPI == 2) {
            v += extra[n];
            v = (v > 20.f) ? v : log1pf(__expf(v));
          }
          C[(size_t)m * N + n] = v;
        }
      }
}

// ---------------- causal depthwise conv (DCONV=4) + SiLU ----------------
__global__ __launch_bounds__(256) void conv_silu_kernel(
    const float* __restrict__ xz, const float* __restrict__ cw,
    const float* __restrict__ cb, float* __restrict__ xc,
    u16* __restrict__ xcb) {
  const int idx = blockIdx.x * 256 + threadIdx.x;  // over M*DIN
  const int d = idx & 2047;
  const int m = idx >> 11;
  const int l = m & 1023;
  const float4 wv = ((const float4*)cw)[d];
  const float w4[4] = {wv.x, wv.y, wv.z, wv.w};
  float acc = cb[d];
#pragma unroll
  for (int k = 0; k < 4; ++k) {
    int lk = l + k - 3;
    if (lk >= 0) acc += xz[(size_t)(m + k - 3) * 4096 + d] * w4[k];
  }
  const float sv = acc / (1.0f + __expf(-acc));  // silu
  xc[idx] = sv;
  xcb[idx] = f2bf(sv);
}

// ---------------- selective scan ----------------
// block = (b, 16 channels d); thread = (d, n). LDS-chunked 64 steps.
template <int CTRL>
__device__ __forceinline__ float dpp_add(float x) {
  int yi = __builtin_amdgcn_update_dpp(0, __float_as_int(x), CTRL, 0xF, 0xF, true);
  return x + __int_as_float(yi);
}

__global__ __launch_bounds__(256) void scan_kernel(
    const float* __restrict__ dt,    // [M,2048] softplus'd
    const float* __restrict__ xc,    // [M,2048]
    const float* __restrict__ xz,    // [M,4096]; z = col 2048+d
    const float* __restrict__ xdbl,  // [M,96]; B = 64..79, C = 80..95
    const float* __restrict__ A_log, // [2048,16]
    const float* __restrict__ Dsk,   // [2048]
    u16* __restrict__ yb) {          // [M,2048] bf16
  const int b = blockIdx.x >> 7;
  const int d0 = (blockIdx.x & 127) * 16;
  const int tid = threadIdx.x;
  const int dg = tid >> 4;
  const int n = tid & 15;
  const int d = d0 + dg;
  const float a_coef = -__expf(A_log[(size_t)d * 16 + n]);  // A[d,n]
  const float Dd = Dsk[d];
  float h = 0.f;

  __shared__ float sdt[64][16];
  __shared__ float sxc[64][16];
  __shared__ float szz[64][16];
  __shared__ float sbc[64][32];

  for (int c = 0; c < 16; ++c) {
    const int mb = b * 1024 + c * 64;
    {
      const int s = tid >> 2, o = (tid & 3) * 4;
      *(float4*)&sdt[s][o] = *(const float4*)&dt[(size_t)(mb + s) * 2048 + d0 + o];
      *(float4*)&sxc[s][o] = *(const float4*)&xc[(size_t)(mb + s) * 2048 + d0 + o];
      *(float4*)&szz[s][o] = *(const float4*)&xz[(size_t)(mb + s) * 4096 + 2048 + d0 + o];
      const int s2 = tid >> 3, o2 = (tid & 7) * 4;
      *(float4*)&sbc[s2][o2] = *(const float4*)&xdbl[(size_t)(mb + s2) * 96 + 64 + o2];
      *(float4*)&sbc[s2 + 32][o2] = *(const float4*)&xdbl[(size_t)(mb + s2 + 32) * 96 + 64 + o2];
    }
    __syncthreads();
#pragma unroll 4
    for (int s = 0; s < 64; ++s) {
      const float dtv = sdt[s][dg];
      const float xcv = sxc[s][dg];
      const float Bn = sbc[s][n];
      const float Cn = sbc[s][16 + n];
      const float da = __expf(dtv * a_coef);
      h = da * h + dtv * xcv * Bn;
      float p = h * Cn;
      p = dpp_add<0x111>(p);  // row_shr:1
      p = dpp_add<0x112>(p);  // row_shr:2
      p = dpp_add<0x114>(p);  // row_shr:4
      p = dpp_add<0x118>(p);  // row_shr:8  -> lane n==15 holds row sum
      if (n == 15) {
        const float zv = szz[s][dg];
        const float sig = 1.0f / (1.0f + __expf(-zv));
        const float yv = (p + xcv * Dd) * (zv * sig);
        yb[(size_t)(mb + s) * 2048 + d] = f2bf(yv);
      }
    }
    __syncthreads();
  }
}

// ---------------- launch ----------------
extern "C" void kernel_launch(void* const* d_in, const int* in_sizes, int n_in,
                              void* d_out, int out_size, void* d_ws, size_t ws_size,
                              hipStream_t stream) {
  const float* x        = (const float*)d_in[0];
  const float* norm_w   = (const float*)d_in[1];
  const float* norm_b   = (const float*)d_in[2];
  const float* in_projw = (const float*)d_in[3];
  const float* conv_w   = (const float*)d_in[4];
  const float* conv_b   = (const float*)d_in[5];
  const float* x_projw  = (const float*)d_in[6];
  const float* dt_projw = (const float*)d_in[7];
  const float* dt_projb = (const float*)d_in[8];
  const float* A_log    = (const float*)d_in[9];
  const float* D_skip   = (const float*)d_in[10];
  const float* out_projw= (const float*)d_in[11];
  float* out = (float*)d_out;

  char* p = (char*)d_ws;
  auto alloc = [&](size_t bytes) {
    char* r = p;
    p += (bytes + 255) & ~(size_t)255;
    return r;
  };
  float* xz   = (float*)alloc(2048ULL * 4096 * 4);  // 32 MB
  float* xc   = (float*)alloc(2048ULL * 2048 * 4);  // 16 MB
  float* dtb  = (float*)alloc(2048ULL * 2048 * 4);  // 16 MB
  float* xdbl = (float*)alloc(2048ULL * 96 * 4);    // 768 KB
  u16* h_bf   = (u16*)alloc(2048ULL * 1024 * 2);    // 4 MB
  u16* xcb    = (u16*)alloc(2048ULL * 2048 * 2);    // 8 MB
  u16* ybf    = (u16*)alloc(2048ULL * 2048 * 2);    // 8 MB
  u16* dtr    = (u16*)alloc(2048ULL * 64 * 2);      // 256 KB
  u16* Wi     = (u16*)alloc(4096ULL * 1024 * 2);    // 8 MB
  u16* Wx     = (u16*)alloc(96ULL * 2048 * 2);      // 384 KB
  u16* Wdt    = (u16*)alloc(2048ULL * 64 * 2);      // 256 KB
  u16* Wo     = (u16*)alloc(1024ULL * 2048 * 2);    // 4 MB
  (void)ws_size; (void)in_sizes; (void)n_in; (void)out_size;

  // weight converts (inputs restored before every launch)
  f32_to_bf16_kernel<<<16384, 256, 0, stream>>>(in_projw, Wi, 4096 * 1024);
  f32_to_bf16_kernel<<<768, 256, 0, stream>>>(x_projw, Wx, 96 * 2048);
  f32_to_bf16_kernel<<<512, 256, 0, stream>>>(dt_projw, Wdt, 2048 * 64);
  f32_to_bf16_kernel<<<8192, 256, 0, stream>>>(out_projw, Wo, 1024 * 2048);

  ln_bf16_kernel<<<2048, 256, 0, stream>>>(x, norm_w, norm_b, h_bf);

  // xz = h @ in_proj_w^T   [2048,4096]
  gemm_bt<0><<<dim3(64, 32), 256, 0, stream>>>(h_bf, Wi, xz, nullptr, 2048, 4096, 1024);

  // conv + silu -> xc (f32 + bf16)
  conv_silu_kernel<<<16384, 256, 0, stream>>>(xz, conv_w, conv_b, xc, xcb);

  // x_dbl = xc @ x_proj_w^T  [2048,96]
  gemm_bt<0><<<dim3(2, 32), 256, 0, stream>>>(xcb, Wx, xdbl, nullptr, 2048, 96, 2048);

  // dt_r bf16
  dtr_bf16_kernel<<<512, 256, 0, stream>>>(xdbl, dtr);

  // dt = softplus(dt_r @ dt_proj_w^T + b)  [2048,2048]
  gemm_bt<2><<<dim3(32, 32), 256, 0, stream>>>(dtr, Wdt, dtb, dt_projb, 2048, 2048, 64);

  // selective scan + gate -> y bf16
  scan_kernel<<<256, 256, 0, stream>>>(dtb, xc, xz, xdbl, A_log, D_skip, ybf);

  // out = x + y @ out_proj_w^T  [2048,1024]
  gemm_bt<1><<<dim3(16, 32), 256, 0, stream>>>(ybf, Wo, out, x, 2048, 1024, 2048);
}

// Round 2
// 323.111 us; speedup vs baseline: 1.3295x; 1.3295x over previous
//
#include <hip/hip_runtime.h>

// Mamba block, MI355X. Pipeline:
//  ln -> bf16 h -> [MFMA gemm] xz -> conv+silu -> [gemm] x_dbl -> [gemm+softplus] dt
//  -> CHUNKED selective scan (3-pass: chunk-local scan, combine, replay+output)
//  -> y_bf16 -> [gemm+resid] out
// Scan chunking: L=1024 split into G=8 chunks of T=128. Linear recurrence
// h_t = a_t h_{t-1} + u_t  =>  h_chunk_end = prodA * h_init + h_partial (exact).

typedef unsigned short u16;
typedef unsigned int u32;

typedef __bf16 bf16x8 __attribute__((ext_vector_type(8)));
typedef float f32x4 __attribute__((ext_vector_type(4)));

#define SCAN_G 8
#define SCAN_T 128
#define NSTATE 65536  // B * DIN * N = 2*2048*16

__device__ __forceinline__ u16 f2bf(float f) {
  u32 u = __float_as_uint(f);
  u32 r = u + 0x7FFFu + ((u >> 16) & 1u);  // RNE
  return (u16)(r >> 16);
}

// ---------------- LayerNorm -> bf16 ----------------
__global__ __launch_bounds__(256) void ln_bf16_kernel(
    const float* __restrict__ x, const float* __restrict__ w,
    const float* __restrict__ b, u16* __restrict__ h) {
  const int row = blockIdx.x;
  const int tid = threadIdx.x;
  const float4 v = ((const float4*)(x + (size_t)row * 1024))[tid];
  float s = v.x + v.y + v.z + v.w;
  float s2 = v.x * v.x + v.y * v.y + v.z * v.z + v.w * v.w;
  for (int off = 32; off >= 1; off >>= 1) {
    s += __shfl_xor(s, off);
    s2 += __shfl_xor(s2, off);
  }
  __shared__ float red[8];
  const int wave = tid >> 6;
  if ((tid & 63) == 0) { red[wave * 2] = s; red[wave * 2 + 1] = s2; }
  __syncthreads();
  s = red[0] + red[2] + red[4] + red[6];
  s2 = red[1] + red[3] + red[5] + red[7];
  const float mu = s * (1.0f / 1024.0f);
  const float var = s2 * (1.0f / 1024.0f) - mu * mu;
  const float rstd = rsqrtf(var + 1e-5f);
  const float4 wv = ((const float4*)w)[tid];
  const float4 bv = ((const float4*)b)[tid];
  ushort4 o;
  o.x = f2bf((v.x - mu) * rstd * wv.x + bv.x);
  o.y = f2bf((v.y - mu) * rstd * wv.y + bv.y);
  o.z = f2bf((v.z - mu) * rstd * wv.z + bv.z);
  o.w = f2bf((v.w - mu) * rstd * wv.w + bv.w);
  ((ushort4*)(h + (size_t)row * 1024))[tid] = o;
}

// ---------------- fp32 -> bf16 converts ----------------
__global__ __launch_bounds__(256) void f32_to_bf16_kernel(
    const float* __restrict__ src, u16* __restrict__ dst, int n) {
  int i = blockIdx.x * 256 + threadIdx.x;
  if (i < n) dst[i] = f2bf(src[i]);
}

// x_dbl[:, :64] -> bf16 [M,64]
__global__ __launch_bounds__(256) void dtr_bf16_kernel(
    const float* __restrict__ xdbl, u16* __restrict__ dst) {
  int i = blockIdx.x * 256 + threadIdx.x;  // 2048*64
  int m = i >> 6, r = i & 63;
  dst[i] = f2bf(xdbl[(size_t)m * 96 + r]);
}

// ---------------- generic bf16 MFMA GEMM, C = A @ W^T ----------------
// A [M,K] bf16 row-major, W [N,K] bf16 row-major, C [M,N] f32.
// EPI: 0 none, 1 C += extra[m*N+n] (residual), 2 C = softplus(C + extra[n])
template <int EPI>
__global__ __launch_bounds__(256) void gemm_bt(
    const u16* __restrict__ A, const u16* __restrict__ W,
    float* __restrict__ C, const float* __restrict__ extra,
    int M, int N, int K) {
  const int n0 = blockIdx.x * 64;
  const int m0 = blockIdx.y * 64;
  __shared__ u16 As[64 * 32];
  __shared__ u16 Ws[64 * 32];
  const int tid = threadIdx.x;
  const int wave = tid >> 6;
  const int lane = tid & 63;
  const int wm = (wave >> 1) * 32;
  const int wn = (wave & 1) * 32;
  const int lrow = tid >> 2;       // 0..63 staging row
  const int lcg = (tid & 3) * 8;   // staging k-chunk (8 bf16 = 16B)
  const int arow = m0 + lrow;
  const int wrow = n0 + lrow;
  f32x4 acc[2][2];
#pragma unroll
  for (int i = 0; i < 2; ++i)
#pragma unroll
    for (int j = 0; j < 2; ++j) acc[i][j] = (f32x4){0.f, 0.f, 0.f, 0.f};

  const int fm = lane & 15;
  const int fk = (lane >> 4) * 8;

  for (int k0 = 0; k0 < K; k0 += 32) {
    uint4 av = *(const uint4*)(A + (size_t)arow * K + k0 + lcg);
    uint4 wv = make_uint4(0u, 0u, 0u, 0u);
    if (wrow < N) wv = *(const uint4*)(W + (size_t)wrow * K + k0 + lcg);
    __syncthreads();
    *(uint4*)(As + lrow * 32 + lcg) = av;
    *(uint4*)(Ws + lrow * 32 + lcg) = wv;
    __syncthreads();
    bf16x8 a0 = *(const bf16x8*)(As + (wm + fm) * 32 + fk);
    bf16x8 a1 = *(const bf16x8*)(As + (wm + 16 + fm) * 32 + fk);
    bf16x8 b0 = *(const bf16x8*)(Ws + (wn + fm) * 32 + fk);
    bf16x8 b1 = *(const bf16x8*)(Ws + (wn + 16 + fm) * 32 + fk);
    acc[0][0] = __builtin_amdgcn_mfma_f32_16x16x32_bf16(a0, b0, acc[0][0], 0, 0, 0);
    acc[0][1] = __builtin_amdgcn_mfma_f32_16x16x32_bf16(a0, b1, acc[0][1], 0, 0, 0);
    acc[1][0] = __builtin_amdgcn_mfma_f32_16x16x32_bf16(a1, b0, acc[1][0], 0, 0, 0);
    acc[1][1] = __builtin_amdgcn_mfma_f32_16x16x32_bf16(a1, b1, acc[1][1], 0, 0, 0);
  }

  const int col = lane & 15;
  const int rbase = (lane >> 4) * 4;
#pragma unroll
  for (int tm = 0; tm < 2; ++tm)
#pragma unroll
    for (int tn = 0; tn < 2; ++tn)
#pragma unroll
      for (int r = 0; r < 4; ++r) {
        int m = m0 + wm + tm * 16 + rbase + r;
        int n = n0 + wn + tn * 16 + col;
        if (n < N) {
          float v = acc[tm][tn][r];
          if (EPI == 1) v += extra[(size_t)m * N + n];
          if (EPI == 2) {
            v += extra[n];
            v = (v > 20.f) ? v : log1pf(__expf(v));
          }
          C[(size_t)m * N + n] = v;
        }
      }
}

// ---------------- causal depthwise conv (DCONV=4) + SiLU ----------------
__global__ __launch_bounds__(256) void conv_silu_kernel(
    const float* __restrict__ xz, const float* __restrict__ cw,
    const float* __restrict__ cb, float* __restrict__ xc,
    u16* __restrict__ xcb) {
  const int idx = blockIdx.x * 256 + threadIdx.x;  // over M*DIN
  const int d = idx & 2047;
  const int m = idx >> 11;
  const int l = m & 1023;
  const float4 wv = ((const float4*)cw)[d];
  const float w4[4] = {wv.x, wv.y, wv.z, wv.w};
  float acc = cb[d];
#pragma unroll
  for (int k = 0; k < 4; ++k) {
    int lk = l + k - 3;
    if (lk >= 0) acc += xz[(size_t)(m + k - 3) * 4096 + d] * w4[k];
  }
  const float sv = acc / (1.0f + __expf(-acc));  // silu
  xc[idx] = sv;
  xcb[idx] = f2bf(sv);
}

// ---------------- chunked selective scan ----------------
// State index sid = (b*2048 + d)*16 + n, 0..65535.
// Pass 1: per time-chunk g (T=128 steps), compute with h_init=0:
//   hend[g][sid], prodA[g][sid].
// Pass 2 (combine): H=0; for g: hinit[g]=H; H = prodA[g]*H + hend[g].
// Pass 3: replay each chunk from hinit[g], full y output + gating.

template <int CTRL>
__device__ __forceinline__ float dpp_add(float x) {
  int yi = __builtin_amdgcn_update_dpp(0, __float_as_int(x), CTRL, 0xF, 0xF, true);
  return x + __int_as_float(yi);
}

// blockIdx decode: g = bx & 7, dgroup = (bx>>3)&127, b = bx>>10
__global__ __launch_bounds__(256) void scan_pass1_kernel(
    const float* __restrict__ dt,    // [M,2048] softplus'd
    const float* __restrict__ xc,    // [M,2048]
    const float* __restrict__ xdbl,  // [M,96]; B = cols 64..79
    const float* __restrict__ A_log, // [2048,16]
    float* __restrict__ hend,        // [G][65536]
    float* __restrict__ prodA) {     // [G][65536]
  const int bx = blockIdx.x;
  const int g = bx & 7;
  const int d0 = ((bx >> 3) & 127) * 16;
  const int b = bx >> 10;
  const int tid = threadIdx.x;
  const int dg = tid >> 4;
  const int n = tid & 15;
  const int d = d0 + dg;
  const float a_coef = -__expf(A_log[(size_t)d * 16 + n]);
  float h = 0.f, pa = 1.f;

  __shared__ float sdt[64][16];
  __shared__ float sxc[64][16];
  __shared__ float sB[64][16];

  for (int c = 0; c < SCAN_T / 64; ++c) {
    const int mb = b * 1024 + g * SCAN_T + c * 64;
    {
      const int s = tid >> 2, o = (tid & 3) * 4;
      *(float4*)&sdt[s][o] = *(const float4*)&dt[(size_t)(mb + s) * 2048 + d0 + o];
      *(float4*)&sxc[s][o] = *(const float4*)&xc[(size_t)(mb + s) * 2048 + d0 + o];
      *(float4*)&sB[s][o] = *(const float4*)&xdbl[(size_t)(mb + s) * 96 + 64 + o];
    }
    __syncthreads();
#pragma unroll 4
    for (int s = 0; s < 64; ++s) {
      const float dtv = sdt[s][dg];
      const float xcv = sxc[s][dg];
      const float Bn = sB[s][n];
      const float da = __expf(dtv * a_coef);
      h = da * h + dtv * xcv * Bn;
      pa *= da;
    }
    __syncthreads();
  }
  const int sid = ((b * 2048 + d) << 4) + n;
  hend[g * NSTATE + sid] = h;
  prodA[g * NSTATE + sid] = pa;
}

__global__ __launch_bounds__(256) void scan_combine_kernel(
    const float* __restrict__ hend, const float* __restrict__ prodA,
    float* __restrict__ hinit) {
  const int sid = blockIdx.x * 256 + threadIdx.x;
  float H = 0.f;
#pragma unroll
  for (int g = 0; g < SCAN_G; ++g) {
    hinit[g * NSTATE + sid] = H;
    H = prodA[g * NSTATE + sid] * H + hend[g * NSTATE + sid];
  }
}

__global__ __launch_bounds__(256) void scan_pass2_kernel(
    const float* __restrict__ dt,    // [M,2048]
    const float* __restrict__ xc,    // [M,2048]
    const float* __restrict__ xz,    // [M,4096]; z = col 2048+d
    const float* __restrict__ xdbl,  // [M,96]; B = 64..79, C = 80..95
    const float* __restrict__ A_log, // [2048,16]
    const float* __restrict__ Dsk,   // [2048]
    const float* __restrict__ hinit, // [G][65536]
    u16* __restrict__ yb) {          // [M,2048] bf16
  const int bx = blockIdx.x;
  const int g = bx & 7;
  const int d0 = ((bx >> 3) & 127) * 16;
  const int b = bx >> 10;
  const int tid = threadIdx.x;
  const int dg = tid >> 4;
  const int n = tid & 15;
  const int d = d0 + dg;
  const float a_coef = -__expf(A_log[(size_t)d * 16 + n]);
  const float Dd = Dsk[d];
  const int sid = ((b * 2048 + d) << 4) + n;
  float h = hinit[g * NSTATE + sid];

  __shared__ float sdt[64][16];
  __shared__ float sxc[64][16];
  __shared__ float szz[64][16];
  __shared__ float sbc[64][32];

  for (int c = 0; c < SCAN_T / 64; ++c) {
    const int mb = b * 1024 + g * SCAN_T + c * 64;
    {
      const int s = tid >> 2, o = (tid & 3) * 4;
      *(float4*)&sdt[s][o] = *(const float4*)&dt[(size_t)(mb + s) * 2048 + d0 + o];
      *(float4*)&sxc[s][o] = *(const float4*)&xc[(size_t)(mb + s) * 2048 + d0 + o];
      *(float4*)&szz[s][o] = *(const float4*)&xz[(size_t)(mb + s) * 4096 + 2048 + d0 + o];
      const int s2 = tid >> 3, o2 = (tid & 7) * 4;
      *(float4*)&sbc[s2][o2] = *(const float4*)&xdbl[(size_t)(mb + s2) * 96 + 64 + o2];
      *(float4*)&sbc[s2 + 32][o2] = *(const float4*)&xdbl[(size_t)(mb + s2 + 32) * 96 + 64 + o2];
    }
    __syncthreads();
#pragma unroll 4
    for (int s = 0; s < 64; ++s) {
      const float dtv = sdt[s][dg];
      const float xcv = sxc[s][dg];
      const float Bn = sbc[s][n];
      const float Cn = sbc[s][16 + n];
      const float da = __expf(dtv * a_coef);
      h = da * h + dtv * xcv * Bn;
      float p = h * Cn;
      p = dpp_add<0x111>(p);  // row_shr:1
      p = dpp_add<0x112>(p);  // row_shr:2
      p = dpp_add<0x114>(p);  // row_shr:4
      p = dpp_add<0x118>(p);  // row_shr:8  -> lane n==15 holds row sum
      if (n == 15) {
        const float zv = szz[s][dg];
        const float sig = 1.0f / (1.0f + __expf(-zv));
        const float yv = (p + xcv * Dd) * (zv * sig);
        yb[(size_t)(mb + s) * 2048 + d] = f2bf(yv);
      }
    }
    __syncthreads();
  }
}

// ---------------- launch ----------------
extern "C" void kernel_launch(void* const* d_in, const int* in_sizes, int n_in,
                              void* d_out, int out_size, void* d_ws, size_t ws_size,
                              hipStream_t stream) {
  const float* x        = (const float*)d_in[0];
  const float* norm_w   = (const float*)d_in[1];
  const float* norm_b   = (const float*)d_in[2];
  const float* in_projw = (const float*)d_in[3];
  const float* conv_w   = (const float*)d_in[4];
  const float* conv_b   = (const float*)d_in[5];
  const float* x_projw  = (const float*)d_in[6];
  const float* dt_projw = (const float*)d_in[7];
  const float* dt_projb = (const float*)d_in[8];
  const float* A_log    = (const float*)d_in[9];
  const float* D_skip   = (const float*)d_in[10];
  const float* out_projw= (const float*)d_in[11];
  float* out = (float*)d_out;

  char* p = (char*)d_ws;
  auto alloc = [&](size_t bytes) {
    char* r = p;
    p += (bytes + 255) & ~(size_t)255;
    return r;
  };
  float* xz   = (float*)alloc(2048ULL * 4096 * 4);  // 32 MB
  float* xc   = (float*)alloc(2048ULL * 2048 * 4);  // 16 MB
  float* dtb  = (float*)alloc(2048ULL * 2048 * 4);  // 16 MB
  float* xdbl = (float*)alloc(2048ULL * 96 * 4);    // 768 KB
  u16* h_bf   = (u16*)alloc(2048ULL * 1024 * 2);    // 4 MB
  u16* xcb    = (u16*)alloc(2048ULL * 2048 * 2);    // 8 MB
  u16* ybf    = (u16*)alloc(2048ULL * 2048 * 2);    // 8 MB
  u16* dtr    = (u16*)alloc(2048ULL * 64 * 2);      // 256 KB
  u16* Wi     = (u16*)alloc(4096ULL * 1024 * 2);    // 8 MB
  u16* Wx     = (u16*)alloc(96ULL * 2048 * 2);      // 384 KB
  u16* Wdt    = (u16*)alloc(2048ULL * 64 * 2);      // 256 KB
  u16* Wo     = (u16*)alloc(1024ULL * 2048 * 2);    // 4 MB
  float* hend = (float*)alloc((size_t)SCAN_G * NSTATE * 4);  // 2 MB
  float* prodA= (float*)alloc((size_t)SCAN_G * NSTATE * 4);  // 2 MB
  float* hinit= (float*)alloc((size_t)SCAN_G * NSTATE * 4);  // 2 MB
  (void)ws_size; (void)in_sizes; (void)n_in; (void)out_size;

  // weight converts (inputs restored before every launch)
  f32_to_bf16_kernel<<<16384, 256, 0, stream>>>(in_projw, Wi, 4096 * 1024);
  f32_to_bf16_kernel<<<768, 256, 0, stream>>>(x_projw, Wx, 96 * 2048);
  f32_to_bf16_kernel<<<512, 256, 0, stream>>>(dt_projw, Wdt, 2048 * 64);
  f32_to_bf16_kernel<<<8192, 256, 0, stream>>>(out_projw, Wo, 1024 * 2048);

  ln_bf16_kernel<<<2048, 256, 0, stream>>>(x, norm_w, norm_b, h_bf);

  // xz = h @ in_proj_w^T   [2048,4096]
  gemm_bt<0><<<dim3(64, 32), 256, 0, stream>>>(h_bf, Wi, xz, nullptr, 2048, 4096, 1024);

  // conv + silu -> xc (f32 + bf16)
  conv_silu_kernel<<<16384, 256, 0, stream>>>(xz, conv_w, conv_b, xc, xcb);

  // x_dbl = xc @ x_proj_w^T  [2048,96]
  gemm_bt<0><<<dim3(2, 32), 256, 0, stream>>>(xcb, Wx, xdbl, nullptr, 2048, 96, 2048);

  // dt_r bf16
  dtr_bf16_kernel<<<512, 256, 0, stream>>>(xdbl, dtr);

  // dt = softplus(dt_r @ dt_proj_w^T + b)  [2048,2048]
  gemm_bt<2><<<dim3(32, 32), 256, 0, stream>>>(dtr, Wdt, dtb, dt_projb, 2048, 2048, 64);

  // chunked selective scan + gate -> y bf16
  scan_pass1_kernel<<<2048, 256, 0, stream>>>(dtb, xc, xdbl, A_log, hend, prodA);
  scan_combine_kernel<<<256, 256, 0, stream>>>(hend, prodA, hinit);
  scan_pass2_kernel<<<2048, 256, 0, stream>>>(dtb, xc, xz, xdbl, A_log, D_skip,
                                              hinit, ybf);

  // out = x + y @ out_proj_w^T  [2048,1024]
  gemm_bt<1><<<dim3(16, 32), 256, 0, stream>>>(ybf, Wo, out, x, 2048, 1024, 2048);
}

// Round 3
// 257.832 us; speedup vs baseline: 1.6661x; 1.2532x over previous
//
#include <hip/hip_runtime.h>

// Mamba block, MI355X.
//  ln -> bf16 h -> [gemm128 MFMA + global_load_lds] xz -> conv+silu
//  -> [gemm64 splitK4] x_dbl (+fused dtr bf16) -> [gemm64+softplus] dt
//  -> CHUNKED selective scan (pass1 state, combine, pass2 replay; b64-packed LDS,
//     LDS y-staging + coalesced gated write phase)
//  -> y_bf16 -> [gemm128 splitK4, bf16 partials] -> out = x + sum(partials)
// ws aliasing: xpart overlays dtb (dead until dt gemm), opart overlays xz
// (dead after pass2) -> total ~103.6 MB unchanged.

typedef unsigned short u16;
typedef unsigned int u32;

typedef __bf16 bf16x8 __attribute__((ext_vector_type(8)));
typedef float f32x4 __attribute__((ext_vector_type(4)));

#define SCAN_G 8
#define NSTATE 65536  // B * DIN * N = 2*2048*16

__device__ __forceinline__ u16 f2bf(float f) {
  u32 u = __float_as_uint(f);
  u32 r = u + 0x7FFFu + ((u >> 16) & 1u);  // RNE
  return (u16)(r >> 16);
}
__device__ __forceinline__ float bf2f(u16 v) {
  return __uint_as_float(((u32)v) << 16);
}

// async global->LDS, 16B per lane; LDS dest = wave-uniform base + lane*16
__device__ __forceinline__ void lds_load16(const u16* g, u16* l) {
  __builtin_amdgcn_global_load_lds(
      (const __attribute__((address_space(1))) u32*)g,
      (__attribute__((address_space(3))) u32*)l, 16, 0, 0);
}

// ---------------- LayerNorm -> bf16 ----------------
__global__ __launch_bounds__(256) void ln_bf16_kernel(
    const float* __restrict__ x, const float* __restrict__ w,
    const float* __restrict__ b, u16* __restrict__ h) {
  const int row = blockIdx.x;
  const int tid = threadIdx.x;
  const float4 v = ((const float4*)(x + (size_t)row * 1024))[tid];
  float s = v.x + v.y + v.z + v.w;
  float s2 = v.x * v.x + v.y * v.y + v.z * v.z + v.w * v.w;
  for (int off = 32; off >= 1; off >>= 1) {
    s += __shfl_xor(s, off);
    s2 += __shfl_xor(s2, off);
  }
  __shared__ float red[8];
  const int wave = tid >> 6;
  if ((tid & 63) == 0) { red[wave * 2] = s; red[wave * 2 + 1] = s2; }
  __syncthreads();
  s = red[0] + red[2] + red[4] + red[6];
  s2 = red[1] + red[3] + red[5] + red[7];
  const float mu = s * (1.0f / 1024.0f);
  const float var = s2 * (1.0f / 1024.0f) - mu * mu;
  const float rstd = rsqrtf(var + 1e-5f);
  const float4 wv = ((const float4*)w)[tid];
  const float4 bv = ((const float4*)b)[tid];
  ushort4 o;
  o.x = f2bf((v.x - mu) * rstd * wv.x + bv.x);
  o.y = f2bf((v.y - mu) * rstd * wv.y + bv.y);
  o.z = f2bf((v.z - mu) * rstd * wv.z + bv.z);
  o.w = f2bf((v.w - mu) * rstd * wv.w + bv.w);
  ((ushort4*)(h + (size_t)row * 1024))[tid] = o;
}

// ---------------- fp32 -> bf16 convert ----------------
__global__ __launch_bounds__(256) void f32_to_bf16_kernel(
    const float* __restrict__ src, u16* __restrict__ dst, int n) {
  int i = blockIdx.x * 256 + threadIdx.x;
  if (i < n) dst[i] = f2bf(src[i]);
}

// ---------------- 64x64-tile bf16 MFMA GEMM, C = A @ W^T ----------------
// EPI: 0 plain f32 store (SPLITK>1: to partial slab blockIdx.z)
//      2 C = softplus(C + extra[n])
template <int EPI, int SPLITK>
__global__ __launch_bounds__(256) void gemm_bt(
    const u16* __restrict__ A, const u16* __restrict__ W,
    float* __restrict__ C, const float* __restrict__ extra,
    int M, int N, int K) {
  const int n0 = blockIdx.x * 64;
  const int m0 = blockIdx.y * 64;
  const int ks = (SPLITK > 1) ? blockIdx.z : 0;
  const int kLen = K / SPLITK;
  const int kOff = ks * kLen;
  float* Cp = (SPLITK > 1) ? (C + (size_t)ks * M * N) : C;
  __shared__ u16 As[64 * 32];
  __shared__ u16 Ws[64 * 32];
  const int tid = threadIdx.x;
  const int wave = tid >> 6;
  const int lane = tid & 63;
  const int wm = (wave >> 1) * 32;
  const int wn = (wave & 1) * 32;
  const int lrow = tid >> 2;
  const int lcg = (tid & 3) * 8;
  const int arow = m0 + lrow;
  const int wrow = n0 + lrow;
  f32x4 acc[2][2];
#pragma unroll
  for (int i = 0; i < 2; ++i)
#pragma unroll
    for (int j = 0; j < 2; ++j) acc[i][j] = (f32x4){0.f, 0.f, 0.f, 0.f};

  const int fm = lane & 15;
  const int fk = (lane >> 4) * 8;

  for (int k0 = kOff; k0 < kOff + kLen; k0 += 32) {
    uint4 av = *(const uint4*)(A + (size_t)arow * K + k0 + lcg);
    uint4 wv = make_uint4(0u, 0u, 0u, 0u);
    if (wrow < N) wv = *(const uint4*)(W + (size_t)wrow * K + k0 + lcg);
    __syncthreads();
    *(uint4*)(As + lrow * 32 + lcg) = av;
    *(uint4*)(Ws + lrow * 32 + lcg) = wv;
    __syncthreads();
    bf16x8 a0 = *(const bf16x8*)(As + (wm + fm) * 32 + fk);
    bf16x8 a1 = *(const bf16x8*)(As + (wm + 16 + fm) * 32 + fk);
    bf16x8 b0 = *(const bf16x8*)(Ws + (wn + fm) * 32 + fk);
    bf16x8 b1 = *(const bf16x8*)(Ws + (wn + 16 + fm) * 32 + fk);
    acc[0][0] = __builtin_amdgcn_mfma_f32_16x16x32_bf16(a0, b0, acc[0][0], 0, 0, 0);
    acc[0][1] = __builtin_amdgcn_mfma_f32_16x16x32_bf16(a0, b1, acc[0][1], 0, 0, 0);
    acc[1][0] = __builtin_amdgcn_mfma_f32_16x16x32_bf16(a1, b0, acc[1][0], 0, 0, 0);
    acc[1][1] = __builtin_amdgcn_mfma_f32_16x16x32_bf16(a1, b1, acc[1][1], 0, 0, 0);
  }

  const int col = lane & 15;
  const int rbase = (lane >> 4) * 4;
#pragma unroll
  for (int tm = 0; tm < 2; ++tm)
#pragma unroll
    for (int tn = 0; tn < 2; ++tn)
#pragma unroll
      for (int r = 0; r < 4; ++r) {
        int m = m0 + wm + tm * 16 + rbase + r;
        int n = n0 + wn + tn * 16 + col;
        if (n < N) {
          float v = acc[tm][tn][r];
          if (EPI == 2) {
            v += extra[n];
            v = (v > 20.f) ? v : log1pf(__expf(v));
          }
          Cp[(size_t)m * N + n] = v;
        }
      }
}

// ---------------- 128x128-tile bf16 MFMA GEMM (m97 structure) ----------------
// EPI: 0 -> f32 C;  3 -> bf16 partial at slab blockIdx.z
template <int EPI, int SPLITK>
__global__ __launch_bounds__(256) void gemm128_kernel(
    const u16* __restrict__ A, const u16* __restrict__ W,
    void* __restrict__ Cout, int M, int N, int K) {
  const int n0 = blockIdx.x * 128;
  const int m0 = blockIdx.y * 128;
  const int ks = (SPLITK > 1) ? blockIdx.z : 0;
  const int kLen = K / SPLITK;
  const int k0 = ks * kLen;
  __shared__ u16 As[128 * 32];
  __shared__ u16 Ws[128 * 32];
  const int tid = threadIdx.x;
  const int wave = tid >> 6;
  const int lane = tid & 63;
  const int wm = (wave >> 1) * 64;
  const int wn = (wave & 1) * 64;
  f32x4 acc[4][4];
#pragma unroll
  for (int i = 0; i < 4; ++i)
#pragma unroll
    for (int j = 0; j < 4; ++j) acc[i][j] = (f32x4){0.f, 0.f, 0.f, 0.f};

  const int fm = lane & 15;
  const int fk = (lane >> 4) * 8;
  const int sr = lane >> 2;       // staging row within 16-row group
  const int sc = (lane & 3) * 8;  // staging col (8 bf16 = 16 B)
  const u16* gA = A + (size_t)(m0 + wave * 32 + sr) * K + k0 + sc;
  const u16* gB = W + (size_t)(n0 + wave * 32 + sr) * K + k0 + sc;
  u16* lA = As + wave * 1024;  // (wave*2+j)*512 elems, j in {0,1}
  u16* lB = Ws + wave * 1024;

  for (int kk = 0; kk < kLen; kk += 32) {
    __syncthreads();
    lds_load16(gA + kk, lA);
    lds_load16(gA + (size_t)16 * K + kk, lA + 512);
    lds_load16(gB + kk, lB);
    lds_load16(gB + (size_t)16 * K + kk, lB + 512);
    __syncthreads();
    bf16x8 af[4], bfr[4];
#pragma unroll
    for (int i = 0; i < 4; ++i)
      af[i] = *(const bf16x8*)(As + (wm + i * 16 + fm) * 32 + fk);
#pragma unroll
    for (int j = 0; j < 4; ++j)
      bfr[j] = *(const bf16x8*)(Ws + (wn + j * 16 + fm) * 32 + fk);
#pragma unroll
    for (int i = 0; i < 4; ++i)
#pragma unroll
      for (int j = 0; j < 4; ++j)
        acc[i][j] = __builtin_amdgcn_mfma_f32_16x16x32_bf16(af[i], bfr[j], acc[i][j], 0, 0, 0);
  }

  const int col = lane & 15;
  const int rb = (lane >> 4) * 4;
#pragma unroll
  for (int i = 0; i < 4; ++i)
#pragma unroll
    for (int j = 0; j < 4; ++j)
#pragma unroll
      for (int r = 0; r < 4; ++r) {
        const int m = m0 + wm + i * 16 + rb + r;
        const int n = n0 + wn + j * 16 + col;
        if (EPI == 0)
          ((float*)Cout)[(size_t)m * N + n] = acc[i][j][r];
        else
          ((u16*)Cout)[(size_t)ks * M * N + (size_t)m * N + n] = f2bf(acc[i][j][r]);
      }
}

// ---------------- x_proj splitK combine + dtr bf16 ----------------
__global__ __launch_bounds__(256) void xproj_comb_kernel(
    const float* __restrict__ part, float* __restrict__ xdbl,
    u16* __restrict__ dtr) {
  const int i = blockIdx.x * 256 + threadIdx.x;  // 2048*96
  const float v = part[i] + part[i + 196608] + part[i + 2 * 196608] +
                  part[i + 3 * 196608];
  xdbl[i] = v;
  const int m = i / 96;
  const int c = i - m * 96;
  if (c < 64) dtr[(size_t)m * 64 + c] = f2bf(v);
}

// ---------------- out splitK combine: out = x + sum(bf16 partials) ----------
__global__ __launch_bounds__(256) void out_comb_kernel(
    const u16* __restrict__ part, const float* __restrict__ x,
    float* __restrict__ out) {
  const int i4 = (blockIdx.x * 256 + threadIdx.x) * 4;  // over 2048*1024
  const float4 xv = *(const float4*)&x[i4];
  float a0 = xv.x, a1 = xv.y, a2 = xv.z, a3 = xv.w;
#pragma unroll
  for (int ks = 0; ks < 4; ++ks) {
    ushort4 pv = *(const ushort4*)&part[(size_t)ks * 2097152 + i4];
    a0 += bf2f(pv.x); a1 += bf2f(pv.y); a2 += bf2f(pv.z); a3 += bf2f(pv.w);
  }
  float4 o = {a0, a1, a2, a3};
  *(float4*)&out[i4] = o;
}

// ---------------- causal depthwise conv (DCONV=4) + SiLU ----------------
__global__ __launch_bounds__(256) void conv_silu_kernel(
    const float* __restrict__ xz, const float* __restrict__ cw,
    const float* __restrict__ cb, float* __restrict__ xc,
    u16* __restrict__ xcb) {
  const int idx = blockIdx.x * 256 + threadIdx.x;  // over M*DIN
  const int d = idx & 2047;
  const int m = idx >> 11;
  const int l = m & 1023;
  const float4 wv = ((const float4*)cw)[d];
  const float w4[4] = {wv.x, wv.y, wv.z, wv.w};
  float acc = cb[d];
#pragma unroll
  for (int k = 0; k < 4; ++k) {
    int lk = l + k - 3;
    if (lk >= 0) acc += xz[(size_t)(m + k - 3) * 4096 + d] * w4[k];
  }
  const float sv = acc / (1.0f + __expf(-acc));  // silu
  xc[idx] = sv;
  xcb[idx] = f2bf(sv);
}

// ---------------- chunked selective scan ----------------
template <int CTRL>
__device__ __forceinline__ float dpp_add(float x) {
  int yi = __builtin_amdgcn_update_dpp(0, __float_as_int(x), CTRL, 0xF, 0xF, true);
  return x + __int_as_float(yi);
}

// grid 2048: g = bx&7, d0 = ((bx>>3)&127)*16, b = bx>>10
__global__ __launch_bounds__(256) void scan_pass1_kernel(
    const float* __restrict__ dt, const float* __restrict__ xc,
    const float* __restrict__ xdbl, const float* __restrict__ A_log,
    float* __restrict__ hend, float* __restrict__ prodA) {
  const int bx = blockIdx.x;
  const int g = bx & 7;
  const int d0 = ((bx >> 3) & 127) * 16;
  const int b = bx >> 10;
  const int tid = threadIdx.x;
  const int dg = tid >> 4;
  const int n = tid & 15;
  const int d = d0 + dg;
  const float a_coef = -__expf(A_log[(size_t)d * 16 + n]);
  float h = 0.f, pa = 1.f;

  __shared__ float sdd[64][16][2];  // {dt, dt*xc}
  __shared__ float sB[64][16];

  const int ss = tid >> 2, q = tid & 3;

  for (int c = 0; c < 2; ++c) {
    const int mb = b * 1024 + g * 128 + c * 64;
    {
      const float4 dt4 = *(const float4*)&dt[(size_t)(mb + ss) * 2048 + d0 + q * 4];
      const float4 xc4 = *(const float4*)&xc[(size_t)(mb + ss) * 2048 + d0 + q * 4];
      float4 p0 = {dt4.x, dt4.x * xc4.x, dt4.y, dt4.y * xc4.y};
      float4 p1 = {dt4.z, dt4.z * xc4.z, dt4.w, dt4.w * xc4.w};
      *(float4*)&sdd[ss][q * 4][0] = p0;
      *(float4*)&sdd[ss][q * 4 + 2][0] = p1;
      *(float4*)&sB[ss][q * 4] =
          *(const float4*)&xdbl[(size_t)(mb + ss) * 96 + 64 + q * 4];
    }
    __syncthreads();
#pragma unroll 8
    for (int s = 0; s < 64; ++s) {
      const float2 ddv = *(const float2*)&sdd[s][dg][0];
      const float Bn = sB[s][n];
      const float da = __expf(ddv.x * a_coef);
      h = __builtin_fmaf(da, h, ddv.y * Bn);
      pa *= da;
    }
    __syncthreads();
  }
  const int sid = ((b * 2048 + d) << 4) + n;
  hend[g * NSTATE + sid] = h;
  prodA[g * NSTATE + sid] = pa;
}

__global__ __launch_bounds__(256) void scan_combine_kernel(
    const float* __restrict__ hend, const float* __restrict__ prodA,
    float* __restrict__ hinit) {
  const int sid = blockIdx.x * 256 + threadIdx.x;
  float H = 0.f;
#pragma unroll
  for (int g = 0; g < SCAN_G; ++g) {
    hinit[g * NSTATE + sid] = H;
    H = prodA[g * NSTATE + sid] * H + hend[g * NSTATE + sid];
  }
}

__global__ __launch_bounds__(256) void scan_pass2_kernel(
    const float* __restrict__ dt, const float* __restrict__ xc,
    const float* __restrict__ xz, const float* __restrict__ xdbl,
    const float* __restrict__ A_log, const float* __restrict__ Dsk,
    const float* __restrict__ hinit, u16* __restrict__ yb) {
  const int bx = blockIdx.x;
  const int g = bx & 7;
  const int d0 = ((bx >> 3) & 127) * 16;
  const int b = bx >> 10;
  const int tid = threadIdx.x;
  const int dg = tid >> 4;
  const int n = tid & 15;
  const int d = d0 + dg;
  const float a_coef = -__expf(A_log[(size_t)d * 16 + n]);
  const int sid = ((b * 2048 + d) << 4) + n;
  float h = hinit[g * NSTATE + sid];
  const int dw = d0 + (tid & 15);  // write-phase channel (constant per thread)
  const float Dw = Dsk[dw];

  __shared__ float sdd[64][16][2];  // {dt, dt*xc}
  __shared__ float sbc[64][16][2];  // {B, C}
  __shared__ float sy[64][16];

  const int ss = tid >> 2, q = tid & 3;

  for (int c = 0; c < 2; ++c) {
    const int mb = b * 1024 + g * 128 + c * 64;
    {
      const float4 dt4 = *(const float4*)&dt[(size_t)(mb + ss) * 2048 + d0 + q * 4];
      const float4 xc4 = *(const float4*)&xc[(size_t)(mb + ss) * 2048 + d0 + q * 4];
      float4 p0 = {dt4.x, dt4.x * xc4.x, dt4.y, dt4.y * xc4.y};
      float4 p1 = {dt4.z, dt4.z * xc4.z, dt4.w, dt4.w * xc4.w};
      *(float4*)&sdd[ss][q * 4][0] = p0;
      *(float4*)&sdd[ss][q * 4 + 2][0] = p1;
      const float4 b4 = *(const float4*)&xdbl[(size_t)(mb + ss) * 96 + 64 + q * 4];
      const float4 c4 = *(const float4*)&xdbl[(size_t)(mb + ss) * 96 + 80 + q * 4];
      sbc[ss][q * 4 + 0][0] = b4.x; sbc[ss][q * 4 + 1][0] = b4.y;
      sbc[ss][q * 4 + 2][0] = b4.z; sbc[ss][q * 4 + 3][0] = b4.w;
      sbc[ss][q * 4 + 0][1] = c4.x; sbc[ss][q * 4 + 1][1] = c4.y;
      sbc[ss][q * 4 + 2][1] = c4.z; sbc[ss][q * 4 + 3][1] = c4.w;
    }
    __syncthreads();
#pragma unroll 8
    for (int s = 0; s < 64; ++s) {
      const float2 ddv = *(const float2*)&sdd[s][dg][0];
      const float2 bcv = *(const float2*)&sbc[s][n][0];
      const float da = __expf(ddv.x * a_coef);
      h = __builtin_fmaf(da, h, ddv.y * bcv.x);
      float p = h * bcv.y;
      p = dpp_add<0x111>(p);
      p = dpp_add<0x112>(p);
      p = dpp_add<0x114>(p);
      p = dpp_add<0x118>(p);  // lane n==15 holds 16-lane sum
      if (n == 15) sy[s][dg] = p;
    }
    __syncthreads();
#pragma unroll
    for (int k = 0; k < 4; ++k) {
      const int idx = k * 256 + tid;
      const int s = idx >> 4;
      const int row = mb + s;
      const float zv = xz[(size_t)row * 4096 + 2048 + dw];
      const float xcv = xc[(size_t)row * 2048 + dw];
      const float sz = zv / (1.0f + __expf(-zv));
      const float yv = (sy[s][tid & 15] + xcv * Dw) * sz;
      yb[(size_t)row * 2048 + dw] = f2bf(yv);
    }
    __syncthreads();
  }
}

// ---------------- launch ----------------
extern "C" void kernel_launch(void* const* d_in, const int* in_sizes, int n_in,
                              void* d_out, int out_size, void* d_ws, size_t ws_size,
                              hipStream_t stream) {
  const float* x        = (const float*)d_in[0];
  const float* norm_w   = (const float*)d_in[1];
  const float* norm_b   = (const float*)d_in[2];
  const float* in_projw = (const float*)d_in[3];
  const float* conv_w   = (const float*)d_in[4];
  const float* conv_b   = (const float*)d_in[5];
  const float* x_projw  = (const float*)d_in[6];
  const float* dt_projw = (const float*)d_in[7];
  const float* dt_projb = (const float*)d_in[8];
  const float* A_log    = (const float*)d_in[9];
  const float* D_skip   = (const float*)d_in[10];
  const float* out_projw= (const float*)d_in[11];
  float* out = (float*)d_out;

  char* p = (char*)d_ws;
  auto alloc = [&](size_t bytes) {
    char* r = p;
    p += (bytes + 255) & ~(size_t)255;
    return r;
  };
  float* xz   = (float*)alloc(2048ULL * 4096 * 4);  // 32 MB
  float* xc   = (float*)alloc(2048ULL * 2048 * 4);  // 16 MB
  float* dtb  = (float*)alloc(2048ULL * 2048 * 4);  // 16 MB
  float* xdbl = (float*)alloc(2048ULL * 96 * 4);    // 768 KB
  u16* h_bf   = (u16*)alloc(2048ULL * 1024 * 2);    // 4 MB
  u16* xcb    = (u16*)alloc(2048ULL * 2048 * 2);    // 8 MB
  u16* ybf    = (u16*)alloc(2048ULL * 2048 * 2);    // 8 MB
  u16* dtr    = (u16*)alloc(2048ULL * 64 * 2);      // 256 KB
  u16* Wi     = (u16*)alloc(4096ULL * 1024 * 2);    // 8 MB
  u16* Wx     = (u16*)alloc(96ULL * 2048 * 2);      // 384 KB
  u16* Wdt    = (u16*)alloc(2048ULL * 64 * 2);      // 256 KB
  u16* Wo     = (u16*)alloc(1024ULL * 2048 * 2);    // 4 MB
  float* hend = (float*)alloc((size_t)SCAN_G * NSTATE * 4);  // 2 MB
  float* prodA= (float*)alloc((size_t)SCAN_G * NSTATE * 4);  // 2 MB
  float* hinit= (float*)alloc((size_t)SCAN_G * NSTATE * 4);  // 2 MB
  // aliases (lifetimes disjoint):
  float* xpart = dtb;        // 4 * 2048*96 f32 = 3 MB, dead before dt gemm
  u16* opart   = (u16*)xz;   // 4 * 2048*1024 bf16 = 16 MB, xz dead after pass2
  (void)ws_size; (void)in_sizes; (void)n_in; (void)out_size;

  // weight converts (inputs restored before every launch)
  f32_to_bf16_kernel<<<16384, 256, 0, stream>>>(in_projw, Wi, 4096 * 1024);
  f32_to_bf16_kernel<<<768, 256, 0, stream>>>(x_projw, Wx, 96 * 2048);
  f32_to_bf16_kernel<<<512, 256, 0, stream>>>(dt_projw, Wdt, 2048 * 64);
  f32_to_bf16_kernel<<<8192, 256, 0, stream>>>(out_projw, Wo, 1024 * 2048);

  ln_bf16_kernel<<<2048, 256, 0, stream>>>(x, norm_w, norm_b, h_bf);

  // xz = h @ in_proj_w^T   [2048,4096], 512 blocks
  gemm128_kernel<0, 1><<<dim3(32, 16), 256, 0, stream>>>(h_bf, Wi, xz, 2048, 4096, 1024);

  // conv + silu -> xc (f32 + bf16)
  conv_silu_kernel<<<16384, 256, 0, stream>>>(xz, conv_w, conv_b, xc, xcb);

  // x_dbl = xc @ x_proj_w^T  [2048,96], splitK=4 -> 256 blocks
  gemm_bt<0, 4><<<dim3(2, 32, 4), 256, 0, stream>>>(xcb, Wx, xpart, nullptr, 2048, 96, 2048);
  xproj_comb_kernel<<<768, 256, 0, stream>>>(xpart, xdbl, dtr);

  // dt = softplus(dt_r @ dt_proj_w^T + b)  [2048,2048]
  gemm_bt<2, 1><<<dim3(32, 32), 256, 0, stream>>>(dtr, Wdt, dtb, dt_projb, 2048, 2048, 64);

  // chunked selective scan + gate -> y bf16
  scan_pass1_kernel<<<2048, 256, 0, stream>>>(dtb, xc, xdbl, A_log, hend, prodA);
  scan_combine_kernel<<<256, 256, 0, stream>>>(hend, prodA, hinit);
  scan_pass2_kernel<<<2048, 256, 0, stream>>>(dtb, xc, xz, xdbl, A_log, D_skip,
                                              hinit, ybf);

  // out partials: y @ out_proj_w^T  [2048,1024], splitK=4 -> 512 blocks
  gemm128_kernel<3, 4><<<dim3(8, 16, 4), 256, 0, stream>>>(ybf, Wo, opart, 2048, 1024, 2048);
  out_comb_kernel<<<2048, 256, 0, stream>>>(opart, x, out);
}

// Round 4
// 249.471 us; speedup vs baseline: 1.7220x; 1.0335x over previous
//
#include <hip/hip_runtime.h>

// Mamba block, MI355X. Round 4: bf16 intermediates (xz, xc, dt), exp2-folded
// scan coefficients, scan_combine folded into pass2, fused weight-convert.
// 11 dispatches:
//  convert_all -> ln -> gemm128(inproj->bf16 xz) -> conv_silu(bf16)
//  -> gemm64 splitK4 (xproj) -> xproj_comb -> gemm64 (dt softplus -> bf16)
//  -> scan_pass1 -> scan_pass2(+combine fold) -> gemm128 splitK4 (outproj)
//  -> out_comb

typedef unsigned short u16;
typedef unsigned int u32;

typedef __bf16 bf16x8 __attribute__((ext_vector_type(8)));
typedef float f32x4 __attribute__((ext_vector_type(4)));

#define SCAN_G 8
#define NSTATE 65536  // B * DIN * N = 2*2048*16

#if __has_builtin(__builtin_amdgcn_exp2f)
#define EXP2F(x) __builtin_amdgcn_exp2f(x)
#else
#define EXP2F(x) exp2f(x)
#endif
#define LOG2E 1.44269504f

__device__ __forceinline__ u16 f2bf(float f) {
  u32 u = __float_as_uint(f);
  u32 r = u + 0x7FFFu + ((u >> 16) & 1u);  // RNE
  return (u16)(r >> 16);
}
__device__ __forceinline__ float bf2f(u16 v) {
  return __uint_as_float(((u32)v) << 16);
}

// async global->LDS, 16B per lane; LDS dest = wave-uniform base + lane*16
__device__ __forceinline__ void lds_load16(const u16* g, u16* l) {
  __builtin_amdgcn_global_load_lds(
      (const __attribute__((address_space(1))) u32*)g,
      (__attribute__((address_space(3))) u32*)l, 16, 0, 0);
}

// ---------------- fused weight converts ----------------
// sizes: Wi 4194304, Wx 196608, Wdt 131072, Wo 2097152 -> total 6619136
__global__ __launch_bounds__(256) void convert_all_kernel(
    const float* __restrict__ w0, const float* __restrict__ w1,
    const float* __restrict__ w2, const float* __restrict__ w3,
    u16* __restrict__ o0, u16* __restrict__ o1,
    u16* __restrict__ o2, u16* __restrict__ o3) {
  const int i = blockIdx.x * 256 + threadIdx.x;
  if (i < 4194304) {
    o0[i] = f2bf(w0[i]);
  } else if (i < 4390912) {
    const int j = i - 4194304;
    o1[j] = f2bf(w1[j]);
  } else if (i < 4521984) {
    const int j = i - 4390912;
    o2[j] = f2bf(w2[j]);
  } else if (i < 6619136) {
    const int j = i - 4521984;
    o3[j] = f2bf(w3[j]);
  }
}

// ---------------- LayerNorm -> bf16 ----------------
__global__ __launch_bounds__(256) void ln_bf16_kernel(
    const float* __restrict__ x, const float* __restrict__ w,
    const float* __restrict__ b, u16* __restrict__ h) {
  const int row = blockIdx.x;
  const int tid = threadIdx.x;
  const float4 v = ((const float4*)(x + (size_t)row * 1024))[tid];
  float s = v.x + v.y + v.z + v.w;
  float s2 = v.x * v.x + v.y * v.y + v.z * v.z + v.w * v.w;
  for (int off = 32; off >= 1; off >>= 1) {
    s += __shfl_xor(s, off);
    s2 += __shfl_xor(s2, off);
  }
  __shared__ float red[8];
  const int wave = tid >> 6;
  if ((tid & 63) == 0) { red[wave * 2] = s; red[wave * 2 + 1] = s2; }
  __syncthreads();
  s = red[0] + red[2] + red[4] + red[6];
  s2 = red[1] + red[3] + red[5] + red[7];
  const float mu = s * (1.0f / 1024.0f);
  const float var = s2 * (1.0f / 1024.0f) - mu * mu;
  const float rstd = rsqrtf(var + 1e-5f);
  const float4 wv = ((const float4*)w)[tid];
  const float4 bv = ((const float4*)b)[tid];
  ushort4 o;
  o.x = f2bf((v.x - mu) * rstd * wv.x + bv.x);
  o.y = f2bf((v.y - mu) * rstd * wv.y + bv.y);
  o.z = f2bf((v.z - mu) * rstd * wv.z + bv.z);
  o.w = f2bf((v.w - mu) * rstd * wv.w + bv.w);
  ((ushort4*)(h + (size_t)row * 1024))[tid] = o;
}

// ---------------- 64x64-tile bf16 MFMA GEMM, C = A @ W^T ----------------
// EPI: 0 f32 store to slab blockIdx.z;  2 bf16 store of softplus(C + extra[n])
template <int EPI, int SPLITK>
__global__ __launch_bounds__(256) void gemm_bt(
    const u16* __restrict__ A, const u16* __restrict__ W,
    void* __restrict__ C, const float* __restrict__ extra,
    int M, int N, int K) {
  const int n0 = blockIdx.x * 64;
  const int m0 = blockIdx.y * 64;
  const int ks = (SPLITK > 1) ? blockIdx.z : 0;
  const int kLen = K / SPLITK;
  const int kOff = ks * kLen;
  __shared__ u16 As[64 * 32];
  __shared__ u16 Ws[64 * 32];
  const int tid = threadIdx.x;
  const int wave = tid >> 6;
  const int lane = tid & 63;
  const int wm = (wave >> 1) * 32;
  const int wn = (wave & 1) * 32;
  const int lrow = tid >> 2;
  const int lcg = (tid & 3) * 8;
  const int arow = m0 + lrow;
  const int wrow = n0 + lrow;
  f32x4 acc[2][2];
#pragma unroll
  for (int i = 0; i < 2; ++i)
#pragma unroll
    for (int j = 0; j < 2; ++j) acc[i][j] = (f32x4){0.f, 0.f, 0.f, 0.f};

  const int fm = lane & 15;
  const int fk = (lane >> 4) * 8;

  for (int k0 = kOff; k0 < kOff + kLen; k0 += 32) {
    uint4 av = *(const uint4*)(A + (size_t)arow * K + k0 + lcg);
    uint4 wv = make_uint4(0u, 0u, 0u, 0u);
    if (wrow < N) wv = *(const uint4*)(W + (size_t)wrow * K + k0 + lcg);
    __syncthreads();
    *(uint4*)(As + lrow * 32 + lcg) = av;
    *(uint4*)(Ws + lrow * 32 + lcg) = wv;
    __syncthreads();
    bf16x8 a0 = *(const bf16x8*)(As + (wm + fm) * 32 + fk);
    bf16x8 a1 = *(const bf16x8*)(As + (wm + 16 + fm) * 32 + fk);
    bf16x8 b0 = *(const bf16x8*)(Ws + (wn + fm) * 32 + fk);
    bf16x8 b1 = *(const bf16x8*)(Ws + (wn + 16 + fm) * 32 + fk);
    acc[0][0] = __builtin_amdgcn_mfma_f32_16x16x32_bf16(a0, b0, acc[0][0], 0, 0, 0);
    acc[0][1] = __builtin_amdgcn_mfma_f32_16x16x32_bf16(a0, b1, acc[0][1], 0, 0, 0);
    acc[1][0] = __builtin_amdgcn_mfma_f32_16x16x32_bf16(a1, b0, acc[1][0], 0, 0, 0);
    acc[1][1] = __builtin_amdgcn_mfma_f32_16x16x32_bf16(a1, b1, acc[1][1], 0, 0, 0);
  }

  const int col = lane & 15;
  const int rbase = (lane >> 4) * 4;
#pragma unroll
  for (int tm = 0; tm < 2; ++tm)
#pragma unroll
    for (int tn = 0; tn < 2; ++tn)
#pragma unroll
      for (int r = 0; r < 4; ++r) {
        int m = m0 + wm + tm * 16 + rbase + r;
        int n = n0 + wn + tn * 16 + col;
        if (n < N) {
          float v = acc[tm][tn][r];
          if (EPI == 0) {
            ((float*)C)[(size_t)ks * M * N + (size_t)m * N + n] = v;
          } else {
            v += extra[n];
            v = (v > 20.f) ? v : log1pf(__expf(v));
            ((u16*)C)[(size_t)m * N + n] = f2bf(v);
          }
        }
      }
}

// ---------------- 128x128-tile bf16 MFMA GEMM (m97 structure) ----------------
// EPI: 4 -> bf16 direct;  3 -> bf16 partial at slab blockIdx.z
template <int EPI, int SPLITK>
__global__ __launch_bounds__(256) void gemm128_kernel(
    const u16* __restrict__ A, const u16* __restrict__ W,
    u16* __restrict__ Cout, int M, int N, int K) {
  const int n0 = blockIdx.x * 128;
  const int m0 = blockIdx.y * 128;
  const int ks = (SPLITK > 1) ? blockIdx.z : 0;
  const int kLen = K / SPLITK;
  const int k0 = ks * kLen;
  __shared__ u16 As[128 * 32];
  __shared__ u16 Ws[128 * 32];
  const int tid = threadIdx.x;
  const int wave = tid >> 6;
  const int lane = tid & 63;
  const int wm = (wave >> 1) * 64;
  const int wn = (wave & 1) * 64;
  f32x4 acc[4][4];
#pragma unroll
  for (int i = 0; i < 4; ++i)
#pragma unroll
    for (int j = 0; j < 4; ++j) acc[i][j] = (f32x4){0.f, 0.f, 0.f, 0.f};

  const int fm = lane & 15;
  const int fk = (lane >> 4) * 8;
  const int sr = lane >> 2;
  const int sc = (lane & 3) * 8;
  const u16* gA = A + (size_t)(m0 + wave * 32 + sr) * K + k0 + sc;
  const u16* gB = W + (size_t)(n0 + wave * 32 + sr) * K + k0 + sc;
  u16* lA = As + wave * 1024;
  u16* lB = Ws + wave * 1024;

  for (int kk = 0; kk < kLen; kk += 32) {
    __syncthreads();
    lds_load16(gA + kk, lA);
    lds_load16(gA + (size_t)16 * K + kk, lA + 512);
    lds_load16(gB + kk, lB);
    lds_load16(gB + (size_t)16 * K + kk, lB + 512);
    __syncthreads();
    bf16x8 af[4], bfr[4];
#pragma unroll
    for (int i = 0; i < 4; ++i)
      af[i] = *(const bf16x8*)(As + (wm + i * 16 + fm) * 32 + fk);
#pragma unroll
    for (int j = 0; j < 4; ++j)
      bfr[j] = *(const bf16x8*)(Ws + (wn + j * 16 + fm) * 32 + fk);
#pragma unroll
    for (int i = 0; i < 4; ++i)
#pragma unroll
      for (int j = 0; j < 4; ++j)
        acc[i][j] = __builtin_amdgcn_mfma_f32_16x16x32_bf16(af[i], bfr[j], acc[i][j], 0, 0, 0);
  }

  const int col = lane & 15;
  const int rb = (lane >> 4) * 4;
#pragma unroll
  for (int i = 0; i < 4; ++i)
#pragma unroll
    for (int j = 0; j < 4; ++j)
#pragma unroll
      for (int r = 0; r < 4; ++r) {
        const int m = m0 + wm + i * 16 + rb + r;
        const int n = n0 + wn + j * 16 + col;
        if (EPI == 4)
          Cout[(size_t)m * N + n] = f2bf(acc[i][j][r]);
        else
          Cout[(size_t)ks * M * N + (size_t)m * N + n] = f2bf(acc[i][j][r]);
      }
}

// ---------------- x_proj splitK combine + dtr bf16 ----------------
__global__ __launch_bounds__(256) void xproj_comb_kernel(
    const float* __restrict__ part, float* __restrict__ xdbl,
    u16* __restrict__ dtr) {
  const int i = blockIdx.x * 256 + threadIdx.x;  // 2048*96
  const float v = part[i] + part[i + 196608] + part[i + 2 * 196608] +
                  part[i + 3 * 196608];
  xdbl[i] = v;
  const int m = i / 96;
  const int c = i - m * 96;
  if (c < 64) dtr[(size_t)m * 64 + c] = f2bf(v);
}

// ---------------- out splitK combine: out = x + sum(bf16 partials) ----------
__global__ __launch_bounds__(256) void out_comb_kernel(
    const u16* __restrict__ part, const float* __restrict__ x,
    float* __restrict__ out) {
  const int i4 = (blockIdx.x * 256 + threadIdx.x) * 4;  // over 2048*1024
  const float4 xv = *(const float4*)&x[i4];
  float a0 = xv.x, a1 = xv.y, a2 = xv.z, a3 = xv.w;
#pragma unroll
  for (int ks = 0; ks < 4; ++ks) {
    ushort4 pv = *(const ushort4*)&part[(size_t)ks * 2097152 + i4];
    a0 += bf2f(pv.x); a1 += bf2f(pv.y); a2 += bf2f(pv.z); a3 += bf2f(pv.w);
  }
  float4 o = {a0, a1, a2, a3};
  *(float4*)&out[i4] = o;
}

// ---------------- causal depthwise conv (DCONV=4) + SiLU, bf16 in/out -------
__global__ __launch_bounds__(256) void conv_silu_kernel(
    const u16* __restrict__ xzb, const float* __restrict__ cw,
    const float* __restrict__ cb, u16* __restrict__ xcb) {
  const int idx = blockIdx.x * 256 + threadIdx.x;  // over M*DIN
  const int d = idx & 2047;
  const int m = idx >> 11;
  const int l = m & 1023;
  const float4 wv = ((const float4*)cw)[d];
  const float w4[4] = {wv.x, wv.y, wv.z, wv.w};
  float acc = cb[d];
#pragma unroll
  for (int k = 0; k < 4; ++k) {
    int lk = l + k - 3;
    if (lk >= 0) acc += bf2f(xzb[(size_t)(m + k - 3) * 4096 + d]) * w4[k];
  }
  const float sv = acc / (1.0f + __expf(-acc));  // silu
  xcb[idx] = f2bf(sv);
}

// ---------------- chunked selective scan ----------------
template <int CTRL>
__device__ __forceinline__ float dpp_add(float x) {
  int yi = __builtin_amdgcn_update_dpp(0, __float_as_int(x), CTRL, 0xF, 0xF, true);
  return x + __int_as_float(yi);
}

// grid 2048: g = bx&7, d0 = ((bx>>3)&127)*16, b = bx>>10
__global__ __launch_bounds__(256) void scan_pass1_kernel(
    const u16* __restrict__ dtb, const u16* __restrict__ xcb,
    const float* __restrict__ xdbl, const float* __restrict__ A_log,
    float* __restrict__ hend, float* __restrict__ prodA) {
  const int bx = blockIdx.x;
  const int g = bx & 7;
  const int d0 = ((bx >> 3) & 127) * 16;
  const int b = bx >> 10;
  const int tid = threadIdx.x;
  const int dg = tid >> 4;
  const int n = tid & 15;
  const int d = d0 + dg;
  const float a2 = -__expf(A_log[(size_t)d * 16 + n]) * LOG2E;  // exp2 domain
  float h = 0.f, cs = 0.f;

  __shared__ float sdd[64][16][2];  // {dt, dt*xc}
  __shared__ float sB[64][16];

  const int ss = tid >> 2, q = tid & 3;

  for (int c = 0; c < 2; ++c) {
    const int mb = b * 1024 + g * 128 + c * 64;
    {
      const ushort4 d4 = *(const ushort4*)&dtb[(size_t)(mb + ss) * 2048 + d0 + q * 4];
      const ushort4 x4 = *(const ushort4*)&xcb[(size_t)(mb + ss) * 2048 + d0 + q * 4];
      const float t0 = bf2f(d4.x), t1 = bf2f(d4.y), t2 = bf2f(d4.z), t3 = bf2f(d4.w);
      float4 p0 = {t0, t0 * bf2f(x4.x), t1, t1 * bf2f(x4.y)};
      float4 p1 = {t2, t2 * bf2f(x4.z), t3, t3 * bf2f(x4.w)};
      *(float4*)&sdd[ss][q * 4][0] = p0;
      *(float4*)&sdd[ss][q * 4 + 2][0] = p1;
      *(float4*)&sB[ss][q * 4] =
          *(const float4*)&xdbl[(size_t)(mb + ss) * 96 + 64 + q * 4];
    }
    __syncthreads();
#pragma unroll 8
    for (int s = 0; s < 64; ++s) {
      const float2 ddv = *(const float2*)&sdd[s][dg][0];
      const float Bn = sB[s][n];
      const float da = EXP2F(ddv.x * a2);
      h = __builtin_fmaf(da, h, ddv.y * Bn);
      cs += ddv.x;
    }
    __syncthreads();
  }
  const int sid = ((b * 2048 + d) << 4) + n;
  hend[g * NSTATE + sid] = h;
  prodA[g * NSTATE + sid] = EXP2F(a2 * cs);
}

__global__ __launch_bounds__(256) void scan_pass2_kernel(
    const u16* __restrict__ dtb, const u16* __restrict__ xcb,
    const u16* __restrict__ xzb, const float* __restrict__ xdbl,
    const float* __restrict__ A_log, const float* __restrict__ Dsk,
    const float* __restrict__ hend, const float* __restrict__ prodA,
    u16* __restrict__ yb) {
  const int bx = blockIdx.x;
  const int g = bx & 7;
  const int d0 = ((bx >> 3) & 127) * 16;
  const int b = bx >> 10;
  const int tid = threadIdx.x;
  const int dg = tid >> 4;
  const int n = tid & 15;
  const int d = d0 + dg;
  const float a2 = -__expf(A_log[(size_t)d * 16 + n]) * LOG2E;
  const int sid = ((b * 2048 + d) << 4) + n;
  // fold of scan_combine: reconstruct h_init for this chunk
  float h = 0.f;
  for (int gp = 0; gp < g; ++gp)
    h = prodA[gp * NSTATE + sid] * h + hend[gp * NSTATE + sid];
  const int dw = d0 + (tid & 15);  // write-phase channel
  const float Dw = Dsk[dw];

  __shared__ float sdd[64][16][2];  // {dt, dt*xc}
  __shared__ float sbc[64][16][2];  // {B, C}
  __shared__ float sy[64][16];

  const int ss = tid >> 2, q = tid & 3;

  for (int c = 0; c < 2; ++c) {
    const int mb = b * 1024 + g * 128 + c * 64;
    {
      const ushort4 d4 = *(const ushort4*)&dtb[(size_t)(mb + ss) * 2048 + d0 + q * 4];
      const ushort4 x4 = *(const ushort4*)&xcb[(size_t)(mb + ss) * 2048 + d0 + q * 4];
      const float t0 = bf2f(d4.x), t1 = bf2f(d4.y), t2 = bf2f(d4.z), t3 = bf2f(d4.w);
      float4 p0 = {t0, t0 * bf2f(x4.x), t1, t1 * bf2f(x4.y)};
      float4 p1 = {t2, t2 * bf2f(x4.z), t3, t3 * bf2f(x4.w)};
      *(float4*)&sdd[ss][q * 4][0] = p0;
      *(float4*)&sdd[ss][q * 4 + 2][0] = p1;
      const float4 b4 = *(const float4*)&xdbl[(size_t)(mb + ss) * 96 + 64 + q * 4];
      const float4 c4 = *(const float4*)&xdbl[(size_t)(mb + ss) * 96 + 80 + q * 4];
      sbc[ss][q * 4 + 0][0] = b4.x; sbc[ss][q * 4 + 1][0] = b4.y;
      sbc[ss][q * 4 + 2][0] = b4.z; sbc[ss][q * 4 + 3][0] = b4.w;
      sbc[ss][q * 4 + 0][1] = c4.x; sbc[ss][q * 4 + 1][1] = c4.y;
      sbc[ss][q * 4 + 2][1] = c4.z; sbc[ss][q * 4 + 3][1] = c4.w;
    }
    __syncthreads();
#pragma unroll 8
    for (int s = 0; s < 64; ++s) {
      const float2 ddv = *(const float2*)&sdd[s][dg][0];
      const float2 bcv = *(const float2*)&sbc[s][n][0];
      const float da = EXP2F(ddv.x * a2);
      h = __builtin_fmaf(da, h, ddv.y * bcv.x);
      float p = h * bcv.y;
      p = dpp_add<0x111>(p);
      p = dpp_add<0x112>(p);
      p = dpp_add<0x114>(p);
      p = dpp_add<0x118>(p);  // lane n==15 holds 16-lane sum
      if (n == 15) sy[s][dg] = p;
    }
    __syncthreads();
#pragma unroll
    for (int k = 0; k < 4; ++k) {
      const int idx = k * 256 + tid;
      const int s = idx >> 4;
      const int row = mb + s;
      const float zv = bf2f(xzb[(size_t)row * 4096 + 2048 + dw]);
      const float xcv = bf2f(xcb[(size_t)row * 2048 + dw]);
      const float sz = zv / (1.0f + __expf(-zv));
      const float yv = (sy[s][tid & 15] + xcv * Dw) * sz;
      yb[(size_t)row * 2048 + dw] = f2bf(yv);
    }
    __syncthreads();
  }
}

// ---------------- launch ----------------
extern "C" void kernel_launch(void* const* d_in, const int* in_sizes, int n_in,
                              void* d_out, int out_size, void* d_ws, size_t ws_size,
                              hipStream_t stream) {
  const float* x        = (const float*)d_in[0];
  const float* norm_w   = (const float*)d_in[1];
  const float* norm_b   = (const float*)d_in[2];
  const float* in_projw = (const float*)d_in[3];
  const float* conv_w   = (const float*)d_in[4];
  const float* conv_b   = (const float*)d_in[5];
  const float* x_projw  = (const float*)d_in[6];
  const float* dt_projw = (const float*)d_in[7];
  const float* dt_projb = (const float*)d_in[8];
  const float* A_log    = (const float*)d_in[9];
  const float* D_skip   = (const float*)d_in[10];
  const float* out_projw= (const float*)d_in[11];
  float* out = (float*)d_out;

  char* p = (char*)d_ws;
  auto alloc = [&](size_t bytes) {
    char* r = p;
    p += (bytes + 255) & ~(size_t)255;
    return r;
  };
  u16* xzb    = (u16*)alloc(2048ULL * 4096 * 2);   // 16 MB (bf16 xz)
  u16* xcb    = (u16*)alloc(2048ULL * 2048 * 2);   // 8 MB
  u16* dtb16  = (u16*)alloc(2048ULL * 2048 * 2);   // 8 MB (bf16 softplus dt)
  float* xdbl = (float*)alloc(2048ULL * 96 * 4);   // 768 KB
  u16* h_bf   = (u16*)alloc(2048ULL * 1024 * 2);   // 4 MB
  u16* ybf    = (u16*)alloc(2048ULL * 2048 * 2);   // 8 MB
  u16* dtr    = (u16*)alloc(2048ULL * 64 * 2);     // 256 KB
  u16* Wi     = (u16*)alloc(4096ULL * 1024 * 2);   // 8 MB
  u16* Wx     = (u16*)alloc(96ULL * 2048 * 2);     // 384 KB
  u16* Wdt    = (u16*)alloc(2048ULL * 64 * 2);     // 256 KB
  u16* Wo     = (u16*)alloc(1024ULL * 2048 * 2);   // 4 MB
  float* hend = (float*)alloc((size_t)SCAN_G * NSTATE * 4);  // 2 MB
  float* prodA= (float*)alloc((size_t)SCAN_G * NSTATE * 4);  // 2 MB
  float* xpart= (float*)alloc(4ULL * 2048 * 96 * 4);         // 3 MB
  // alias: out partials (16 MB bf16) over xzb -- xzb dead after scan_pass2
  u16* opart  = xzb;
  (void)ws_size; (void)in_sizes; (void)n_in; (void)out_size;

  // all weight converts in one dispatch
  convert_all_kernel<<<25856, 256, 0, stream>>>(in_projw, x_projw, dt_projw,
                                                out_projw, Wi, Wx, Wdt, Wo);

  ln_bf16_kernel<<<2048, 256, 0, stream>>>(x, norm_w, norm_b, h_bf);

  // xz = h @ in_proj_w^T   [2048,4096] -> bf16
  gemm128_kernel<4, 1><<<dim3(32, 16), 256, 0, stream>>>(h_bf, Wi, xzb, 2048, 4096, 1024);

  // conv + silu -> xc bf16
  conv_silu_kernel<<<16384, 256, 0, stream>>>(xzb, conv_w, conv_b, xcb);

  // x_dbl = xc @ x_proj_w^T  [2048,96], splitK=4
  gemm_bt<0, 4><<<dim3(2, 32, 4), 256, 0, stream>>>(xcb, Wx, xpart, nullptr, 2048, 96, 2048);
  xproj_comb_kernel<<<768, 256, 0, stream>>>(xpart, xdbl, dtr);

  // dt = softplus(dt_r @ dt_proj_w^T + b)  [2048,2048] -> bf16
  gemm_bt<2, 1><<<dim3(32, 32), 256, 0, stream>>>(dtr, Wdt, dtb16, dt_projb, 2048, 2048, 64);

  // chunked selective scan (combine folded into pass2)
  scan_pass1_kernel<<<2048, 256, 0, stream>>>(dtb16, xcb, xdbl, A_log, hend, prodA);
  scan_pass2_kernel<<<2048, 256, 0, stream>>>(dtb16, xcb, xzb, xdbl, A_log, D_skip,
                                              hend, prodA, ybf);

  // out partials: y @ out_proj_w^T  [2048,1024], splitK=4 (opart aliases xzb)
  gemm128_kernel<3, 4><<<dim3(8, 16, 4), 256, 0, stream>>>(ybf, Wo, opart, 2048, 1024, 2048);
  out_comb_kernel<<<2048, 256, 0, stream>>>(opart, x, out);
}